// Round 3
// baseline (438.056 us; speedup 1.0000x reference)
//
#include <hip/hip_runtime.h>
#include <stdint.h>

// NARM fused pipeline v3 for MI355X (gfx950).
//   k_prep : zero carry slots + cumsum state
//   k_scan : fused dual-GRU recurrence; raw s_barrier (lgkmcnt-only) per step
//            so x-prefetch + h-stores stay in flight across the barrier
//   k_score: grid = tc (one block per t); A1/A2 staged to LDS once per block
//   k_cum  : LDS-staged cumsum of score*h_l, capture t in [L_b-4, L_b-1], +h_g

typedef __attribute__((ext_vector_type(8))) short short8;
typedef __attribute__((ext_vector_type(4))) float float4v;

// exec-sync barrier WITHOUT the vmcnt(0) drain __syncthreads() would emit.
// lgkmcnt(0) makes this wave's LDS reads/writes visible; s_barrier rendezvous.
// Global loads/stores (x prefetch, h stores) remain in flight — they are
// per-thread private, never read by another wave in this kernel.
#define LDS_BARRIER() asm volatile("s_waitcnt lgkmcnt(0)\n\ts_barrier" ::: "memory")

__device__ inline float bf2f(unsigned short u){
  union { unsigned int i; float f; } v; v.i = ((unsigned int)u) << 16; return v.f;
}
__device__ inline unsigned short f2bf(float f){
  union { float f; unsigned int i; } v; v.f = f;
  unsigned int x = v.i;
  return (unsigned short)((x + 0x7fffu + ((x >> 16) & 1u)) >> 16);
}
__device__ inline unsigned int pack2(float a, float b){
  return (unsigned int)f2bf(a) | ((unsigned int)f2bf(b) << 16);
}
__device__ inline float sigm(float x){ return __builtin_amdgcn_rcpf(1.0f + __expf(-x)); }
__device__ inline float tanhfast(float x){ return 1.0f - 2.0f * __builtin_amdgcn_rcpf(__expf(2.0f * x) + 1.0f); }

// ---------------- K0: prep (zero carries + cum) ----------------
__global__ void k_prep(unsigned short* hl_slot, unsigned short* hg_slot, float* cum)
{
  int i = blockIdx.x * blockDim.x + threadIdx.x;   // grid 512*256 = 131072
  hl_slot[i] = 0;
  hg_slot[i] = 0;
  cum[i] = 0.0f;
}

// ---------------- K1: fused dual-GRU scan ----------------
// grid 128 = (64 batch-groups x 2 GRUs), block 512 (8 waves, 16 cols each).
__global__ __launch_bounds__(512, 2) void k_scan(
    const float* __restrict__ x,
    const float* __restrict__ Wih_g, const float* __restrict__ Whh_g,
    const float* __restrict__ bih_g, const float* __restrict__ bhh_g,
    const float* __restrict__ Wih_l, const float* __restrict__ Whh_l,
    const float* __restrict__ bih_l, const float* __restrict__ bhh_l,
    unsigned short* __restrict__ hl_seq, unsigned short* __restrict__ hg_seq,
    int tc, int t0)
{
  __shared__ __align__(16) unsigned short hbuf[2][16][136];
  __shared__ __align__(16) unsigned short xbuf[2][16][136];
  int tid = threadIdx.x;
  int w = tid >> 6, L = tid & 63, l15 = L & 15, q = L >> 4;
  int gru = blockIdx.x & 1;                 // 0 = g, 1 = l
  int b0 = (blockIdx.x >> 1) * 16;
  const float* Wih = gru ? Wih_l : Wih_g;
  const float* Whh = gru ? Whh_l : Whh_g;
  const float* bih = gru ? bih_l : bih_g;
  const float* bhh = gru ? bhh_l : bhh_g;
  unsigned short* myseq = gru ? hl_seq : hg_seq;

  int col = w * 16 + l15;                   // this lane's output column

  // register-resident weight B-fragments (fp32 -> bf16 once per launch)
  short8 Wi[3][4], Wh[3][4];
  #pragma unroll
  for (int G = 0; G < 3; G++) {
    int row = G * 128 + col;
    #pragma unroll
    for (int kf = 0; kf < 4; kf++) {
      const float4* p0 = (const float4*)(Wih + (size_t)row * 128 + kf * 32 + q * 8);
      const float4* p1 = (const float4*)(Whh + (size_t)row * 128 + kf * 32 + q * 8);
      float4 a0 = p0[0], a1 = p0[1], b0f = p1[0], b1f = p1[1];
      short8 si, sh;
      si[0]=(short)f2bf(a0.x); si[1]=(short)f2bf(a0.y); si[2]=(short)f2bf(a0.z); si[3]=(short)f2bf(a0.w);
      si[4]=(short)f2bf(a1.x); si[5]=(short)f2bf(a1.y); si[6]=(short)f2bf(a1.z); si[7]=(short)f2bf(a1.w);
      sh[0]=(short)f2bf(b0f.x); sh[1]=(short)f2bf(b0f.y); sh[2]=(short)f2bf(b0f.z); sh[3]=(short)f2bf(b0f.w);
      sh[4]=(short)f2bf(b1f.x); sh[5]=(short)f2bf(b1f.y); sh[6]=(short)f2bf(b1f.z); sh[7]=(short)f2bf(b1f.w);
      Wi[G][kf] = si; Wh[G][kf] = sh;
    }
  }
  float br  = bih[col]       + bhh[col];
  float bz  = bih[128 + col] + bhh[128 + col];
  float bin = bih[256 + col];               // bhh_n stays inside r*( ) per PyTorch GRU
  float bnh = bhh[256 + col];

  // init h from carry slot (zeroed by k_prep for chunk 0)
  float hold[4];
  #pragma unroll
  for (int r = 0; r < 4; r++) {
    int m = q * 4 + r;
    unsigned short u = myseq[((size_t)(tc - 1) * 1024 + b0 + m) * 128 + col];
    hold[r] = bf2f(u);
    hbuf[0][m][col] = u;
  }
  // stage x(t0), prefetch x(t0+1)
  {
    float4 x0 = ((const float4*)(x + ((size_t)t0 * 1024 + b0) * 128))[tid];
    int row = tid >> 5, c4 = (tid & 31) * 4;
    *(uint2*)&xbuf[0][row][c4] = make_uint2(pack2(x0.x, x0.y), pack2(x0.z, x0.w));
  }
  int tn = t0 + (tc > 1 ? 1 : 0);
  float4 xr = ((const float4*)(x + ((size_t)tn * 1024 + b0) * 128))[tid];
  __syncthreads();

  int p = 0;
  for (int s = 0; s < tc; s++) {
    // A-fragments from LDS
    short8 Ah[4], Ax[4];
    #pragma unroll
    for (int kf = 0; kf < 4; kf++) {
      Ah[kf] = *(const short8*)&hbuf[p][l15][kf * 32 + q * 8];
      Ax[kf] = *(const short8*)&xbuf[p][l15][kf * 32 + q * 8];
    }
    // commit prefetched x(s+1) to the other buffer (safe: last read pre-barrier)
    if (s + 1 < tc) {
      int row = tid >> 5, c4 = (tid & 31) * 4;
      *(uint2*)&xbuf[1 - p][row][c4] = make_uint2(pack2(xr.x, xr.y), pack2(xr.z, xr.w));
    }
    // issue prefetch of x(s+2) — a full step of latency cover
    {
      int t2 = t0 + (s + 2 < tc ? s + 2 : tc - 1);
      xr = ((const float4*)(x + ((size_t)t2 * 1024 + b0) * 128))[tid];
    }
    // MFMA: r,z accumulate x-proj + h-proj; n keeps them separate
    float4v arz0 = (float4v){0.f,0.f,0.f,0.f};
    float4v arz1 = (float4v){0.f,0.f,0.f,0.f};
    float4v anx  = (float4v){0.f,0.f,0.f,0.f};
    float4v anh  = (float4v){0.f,0.f,0.f,0.f};
    #pragma unroll
    for (int kf = 0; kf < 4; kf++) arz0 = __builtin_amdgcn_mfma_f32_16x16x32_bf16(Ax[kf], Wi[0][kf], arz0, 0,0,0);
    #pragma unroll
    for (int kf = 0; kf < 4; kf++) arz1 = __builtin_amdgcn_mfma_f32_16x16x32_bf16(Ax[kf], Wi[1][kf], arz1, 0,0,0);
    #pragma unroll
    for (int kf = 0; kf < 4; kf++) anx  = __builtin_amdgcn_mfma_f32_16x16x32_bf16(Ax[kf], Wi[2][kf], anx,  0,0,0);
    #pragma unroll
    for (int kf = 0; kf < 4; kf++) anh  = __builtin_amdgcn_mfma_f32_16x16x32_bf16(Ah[kf], Wh[2][kf], anh,  0,0,0);
    #pragma unroll
    for (int kf = 0; kf < 4; kf++) arz0 = __builtin_amdgcn_mfma_f32_16x16x32_bf16(Ah[kf], Wh[0][kf], arz0, 0,0,0);
    #pragma unroll
    for (int kf = 0; kf < 4; kf++) arz1 = __builtin_amdgcn_mfma_f32_16x16x32_bf16(Ah[kf], Wh[1][kf], arz1, 0,0,0);

    // gates (fp32 state in registers)
    #pragma unroll
    for (int r = 0; r < 4; r++) {
      int m = q * 4 + r;
      float rr = sigm(arz0[r] + br);
      float zz = sigm(arz1[r] + bz);
      float nn = tanhfast(anx[r] + bin + rr * (anh[r] + bnh));
      float hn = nn + zz * (hold[r] - nn);
      hold[r] = hn;
      unsigned short hu = f2bf(hn);
      hbuf[1 - p][m][col] = hu;
      myseq[((size_t)s * 1024 + b0 + m) * 128 + col] = hu;
    }
    p ^= 1;
    LDS_BARRIER();   // exec+LDS sync only; x prefetch & h stores stay in flight
  }
}

// ---------------- K2: attention score ----------------
// grid tc (one block per timestep), block 256 (4 waves). A1/A2 staged once.
__global__ __launch_bounds__(256) void k_score(const unsigned short* __restrict__ hl_seq,
                                               const unsigned short* __restrict__ hg_seq,
                                               const float* __restrict__ A1,
                                               const float* __restrict__ A2,
                                               const float* __restrict__ v1,
                                               float* __restrict__ score, int tc)
{
  __shared__ __align__(16) unsigned short M1[128][136];
  __shared__ __align__(16) unsigned short M2[128][136];
  int tid = threadIdx.x;
  int w = tid >> 6, L = tid & 63;
  int l15 = L & 15, q = L >> 4;
  int s = blockIdx.x;

  // stage A1, A2 (fp32 -> bf16) once
  #pragma unroll
  for (int it = 0; it < 16; it++) {
    int f4 = it * 256 + tid;                 // 0..4095
    float4 a = ((const float4*)A1)[f4];
    float4 b = ((const float4*)A2)[f4];
    *(uint2*)&M1[f4 >> 5][(f4 & 31) * 4] = make_uint2(pack2(a.x, a.y), pack2(a.z, a.w));
    *(uint2*)&M2[f4 >> 5][(f4 & 31) * 4] = make_uint2(pack2(b.x, b.y), pack2(b.z, b.w));
  }
  __syncthreads();

  float v1v[8];
  #pragma unroll
  for (int nt = 0; nt < 8; nt++) v1v[nt] = v1[nt * 16 + l15];

  // 16 b-tiles per wave, 1-deep fragment prefetch
  short8 Fl[4], Fg[4], Pl[4], Pg[4];
  {
    size_t base = ((size_t)s * 1024 + (size_t)w * 16 + l15) * 128;
    #pragma unroll
    for (int kf = 0; kf < 4; kf++) {
      Fl[kf] = *(const short8*)(hl_seq + base + kf * 32 + q * 8);
      Fg[kf] = *(const short8*)(hg_seq + base + kf * 32 + q * 8);
    }
  }
  for (int it = 0; it < 16; it++) {
    int b0 = (it * 4 + w) * 16;
    if (it + 1 < 16) {
      size_t base = ((size_t)s * 1024 + (size_t)((it + 1) * 4 + w) * 16 + l15) * 128;
      #pragma unroll
      for (int kf = 0; kf < 4; kf++) {
        Pl[kf] = *(const short8*)(hl_seq + base + kf * 32 + q * 8);
        Pg[kf] = *(const short8*)(hg_seq + base + kf * 32 + q * 8);
      }
    }
    float4v acc[8];
    #pragma unroll
    for (int nt = 0; nt < 8; nt++) {
      float4v a = (float4v){0.f, 0.f, 0.f, 0.f};
      #pragma unroll
      for (int kf = 0; kf < 4; kf++)
        a = __builtin_amdgcn_mfma_f32_16x16x32_bf16(
            Fl[kf], *(const short8*)&M1[nt * 16 + l15][kf * 32 + q * 8], a, 0, 0, 0);
      #pragma unroll
      for (int kf = 0; kf < 4; kf++)
        a = __builtin_amdgcn_mfma_f32_16x16x32_bf16(
            Fg[kf], *(const short8*)&M2[nt * 16 + l15][kf * 32 + q * 8], a, 0, 0, 0);
      acc[nt] = a;
    }
    float p4[4];
    #pragma unroll
    for (int r = 0; r < 4; r++) {
      float sum = 0.f;
      #pragma unroll
      for (int nt = 0; nt < 8; nt++) sum += v1v[nt] * sigm(acc[nt][r]);
      sum += __shfl_xor(sum, 1, 16);
      sum += __shfl_xor(sum, 2, 16);
      sum += __shfl_xor(sum, 4, 16);
      sum += __shfl_xor(sum, 8, 16);
      p4[r] = sum;
    }
    if (l15 == 0) {
      #pragma unroll
      for (int r = 0; r < 4; r++)
        score[(size_t)(b0 + q * 4 + r) * tc + s] = p4[r];   // layout [b][tc]
    }
    #pragma unroll
    for (int kf = 0; kf < 4; kf++) { Fl[kf] = Pl[kf]; Fg[kf] = Pg[kf]; }
  }
}

// ---------------- K3: cumsum + capture (LDS-staged) ----------------
// grid 512, block 256: 2 batch rows/block, thread = (b2, j)
__global__ __launch_bounds__(256) void k_cum(const float* __restrict__ score,
                                             const unsigned short* __restrict__ hl_seq,
                                             const unsigned short* __restrict__ hg_seq,
                                             const int* __restrict__ lengths,
                                             float* __restrict__ cum,
                                             float* __restrict__ out, int tc, int t0)
{
  __shared__ __align__(16) unsigned short hlL[100 * 256];  // [s_seg][b2*128+j]
  __shared__ float scL[2][100];
  int tid = threadIdx.x;
  int b2 = tid >> 7, j = tid & 127;
  int b0 = blockIdx.x * 2;
  int b = b0 + b2;
  int base = b2 * 128 + j;

  float c = cum[(size_t)b * 128 + j];
  int cap0 = lengths[b] - 4;                // capture window [cap0, cap0+3] in [0,199]

  // preload the (<=4) h_g capture values that fall in this chunk
  float hgv[4];
  #pragma unroll
  for (int d = 0; d < 4; d++) {
    int sl = cap0 + d - t0;
    hgv[d] = (sl >= 0 && sl < tc) ? bf2f(hg_seq[((size_t)sl * 1024 + b) * 128 + j]) : 0.f;
  }

  for (int seg = 0; seg < tc; seg += 100) {
    int len = (tc - seg < 100) ? (tc - seg) : 100;
    __syncthreads();                         // protect LDS reuse across segments
    // stage hl rows [seg, seg+len) : coalesced short8
    for (int f8 = tid; f8 < len * 32; f8 += 256) {
      int sl = f8 >> 5, r8 = f8 & 31;
      *(short8*)&hlL[(size_t)f8 * 8] =
          *(const short8*)(hl_seq + ((size_t)(seg + sl) * 1024 + b0) * 128 + r8 * 8);
    }
    // stage score rows (contiguous per b: layout [b][tc])
    for (int i = tid; i < 2 * len; i += 256) {
      int bb = (i >= len) ? 1 : 0;
      int sl = i - bb * len;
      scL[bb][sl] = score[(size_t)(b0 + bb) * tc + seg + sl];
    }
    __syncthreads();

    int sl = 0;
    for (; sl + 5 <= len; sl += 5) {
      float h[5], sc[5];
      #pragma unroll
      for (int k = 0; k < 5; k++) {
        h[k] = bf2f(hlL[(size_t)(sl + k) * 256 + base]);
        sc[k] = scL[b2][sl + k];
      }
      #pragma unroll
      for (int k = 0; k < 5; k++) {
        c += sc[k] * h[k];
        int d = (t0 + seg + sl + k) - cap0;
        if ((unsigned)d < 4u)
          out[((size_t)b * 4 + d) * 128 + j] = c + hgv[d];
      }
    }
    for (; sl < len; sl++) {
      c += scL[b2][sl] * bf2f(hlL[(size_t)sl * 256 + base]);
      int d = (t0 + seg + sl) - cap0;
      if ((unsigned)d < 4u)
        out[((size_t)b * 4 + d) * 128 + j] = c + hgv[d];
    }
  }
  cum[(size_t)b * 128 + j] = c;
}

// ---------------- launch ----------------
extern "C" void kernel_launch(void* const* d_in, const int* in_sizes, int n_in,
                              void* d_out, int out_size, void* d_ws, size_t ws_size,
                              hipStream_t stream)
{
  const float* x     = (const float*)d_in[0];
  const int* lengths = (const int*)d_in[1];
  const float* Wih_g = (const float*)d_in[2];
  const float* Whh_g = (const float*)d_in[3];
  const float* bih_g = (const float*)d_in[4];
  const float* bhh_g = (const float*)d_in[5];
  const float* Wih_l = (const float*)d_in[6];
  const float* Whh_l = (const float*)d_in[7];
  const float* bih_l = (const float*)d_in[8];
  const float* bhh_l = (const float*)d_in[9];
  const float* A1    = (const float*)d_in[10];
  const float* A2    = (const float*)d_in[11];
  const float* v1    = (const float*)d_in[12];
  float* out = (float*)d_out;

  // pick largest time-chunk that fits the workspace
  const int cands[8] = {200, 100, 50, 25, 10, 5, 2, 1};
  int tc = 0;
  for (int i = 0; i < 8; i++) {
    int T = cands[i];
    size_t need = 2 * (size_t)T * 1024 * 128 * 2   // hl, hg bf16
                + (size_t)T * 1024 * 4             // score fp32 [b][tc]
                + 524288;                          // cum fp32
    if (need <= ws_size) { tc = T; break; }
  }
  if (!tc) return;

  char* wsb = (char*)d_ws;
  size_t o = 0;
  unsigned short* hl  = (unsigned short*)(wsb + o); o += (size_t)tc * 1024 * 128 * 2;
  unsigned short* hg  = (unsigned short*)(wsb + o); o += (size_t)tc * 1024 * 128 * 2;
  float* score = (float*)(wsb + o); o += (size_t)tc * 1024 * 4;
  float* cum   = (float*)(wsb + o);

  unsigned short* hl_slot = hl + (size_t)(tc - 1) * 1024 * 128;
  unsigned short* hg_slot = hg + (size_t)(tc - 1) * 1024 * 128;

  k_prep<<<512, 256, 0, stream>>>(hl_slot, hg_slot, cum);
  int nch = 200 / tc;
  for (int c = 0; c < nch; c++) {
    k_scan<<<128, 512, 0, stream>>>(x, Wih_g, Whh_g, bih_g, bhh_g,
                                    Wih_l, Whh_l, bih_l, bhh_l, hl, hg, tc, c * tc);
    k_score<<<tc, 256, 0, stream>>>(hl, hg, A1, A2, v1, score, tc);
    k_cum<<<512, 256, 0, stream>>>(score, hl, hg, lengths, cum, out, tc, c * tc);
  }
}

// Round 4
// 402.069 us; speedup vs baseline: 1.0895x; 1.0895x over previous
//
#include <hip/hip_runtime.h>
#include <stdint.h>

// NARM fused pipeline v4 for MI355X (gfx950).
//   k_prep : zero carry slots + cum; cast A1/A2 -> bf16
//   k_scan : fused dual-GRU recurrence; unroll-x2 pingpong; split MFMA chains;
//            shared-rcp gates; hoisted store pointers
//   k_score: grid (tc,2), 512 thr; A1/A2 bf16 staged once per block
//   k_cum  : LDS-staged cumsum of score*h_l, capture t in [L_b-4, L_b-1], +h_g

typedef __attribute__((ext_vector_type(8))) short short8;
typedef __attribute__((ext_vector_type(4))) float float4v;

// exec+LDS barrier without the full vmcnt drain of __syncthreads()
#define LDS_BARRIER() asm volatile("s_waitcnt lgkmcnt(0)\n\ts_barrier" ::: "memory")

__device__ inline float bf2f(unsigned short u){
  union { unsigned int i; float f; } v; v.i = ((unsigned int)u) << 16; return v.f;
}
__device__ inline unsigned short f2bf(float f){
  union { float f; unsigned int i; } v; v.f = f;
  unsigned int x = v.i;
  return (unsigned short)((x + 0x7fffu + ((x >> 16) & 1u)) >> 16);
}
__device__ inline unsigned int pack2(float a, float b){
  return (unsigned int)f2bf(a) | ((unsigned int)f2bf(b) << 16);
}
__device__ inline float sigm(float x){ return __builtin_amdgcn_rcpf(1.0f + __expf(-x)); }

// ---------------- K0: prep ----------------
__global__ void k_prep(unsigned short* hl_slot, unsigned short* hg_slot, float* cum,
                       const float* A1, const float* A2, unsigned short* a12)
{
  int i = blockIdx.x * blockDim.x + threadIdx.x;   // grid 512*256 = 131072
  hl_slot[i] = 0;
  hg_slot[i] = 0;
  cum[i] = 0.0f;
  if (i < 32768) {
    a12[i] = f2bf((i < 16384) ? A1[i] : A2[i - 16384]);
  }
}

// ---------------- K1: fused dual-GRU scan ----------------
// grid 128 = (64 batch-groups x 2 GRUs), block 512 (8 waves, 16 cols each).
__global__ __launch_bounds__(512, 2) void k_scan(
    const float* __restrict__ x,
    const float* __restrict__ Wih_g, const float* __restrict__ Whh_g,
    const float* __restrict__ bih_g, const float* __restrict__ bhh_g,
    const float* __restrict__ Wih_l, const float* __restrict__ Whh_l,
    const float* __restrict__ bih_l, const float* __restrict__ bhh_l,
    unsigned short* __restrict__ hl_seq, unsigned short* __restrict__ hg_seq,
    int tc, int t0)
{
  __shared__ __align__(16) unsigned short hbuf[2][16][136];
  __shared__ __align__(16) unsigned short xbuf[2][16][136];
  int tid = threadIdx.x;
  int w = tid >> 6, L = tid & 63, l15 = L & 15, q = L >> 4;
  int gru = blockIdx.x & 1;                 // 0 = g, 1 = l
  int b0 = (blockIdx.x >> 1) * 16;
  const float* Wih = gru ? Wih_l : Wih_g;
  const float* Whh = gru ? Whh_l : Whh_g;
  const float* bih = gru ? bih_l : bih_g;
  const float* bhh = gru ? bhh_l : bhh_g;
  unsigned short* myseq = gru ? hl_seq : hg_seq;

  int col = w * 16 + l15;                   // this lane's output column

  // register-resident weight B-fragments (fp32 -> bf16 once per launch)
  short8 Wi[3][4], Wh[3][4];
  #pragma unroll
  for (int G = 0; G < 3; G++) {
    int row = G * 128 + col;
    #pragma unroll
    for (int kf = 0; kf < 4; kf++) {
      const float4* p0 = (const float4*)(Wih + (size_t)row * 128 + kf * 32 + q * 8);
      const float4* p1 = (const float4*)(Whh + (size_t)row * 128 + kf * 32 + q * 8);
      float4 a0 = p0[0], a1 = p0[1], b0f = p1[0], b1f = p1[1];
      short8 si, sh;
      si[0]=(short)f2bf(a0.x); si[1]=(short)f2bf(a0.y); si[2]=(short)f2bf(a0.z); si[3]=(short)f2bf(a0.w);
      si[4]=(short)f2bf(a1.x); si[5]=(short)f2bf(a1.y); si[6]=(short)f2bf(a1.z); si[7]=(short)f2bf(a1.w);
      sh[0]=(short)f2bf(b0f.x); sh[1]=(short)f2bf(b0f.y); sh[2]=(short)f2bf(b0f.z); sh[3]=(short)f2bf(b0f.w);
      sh[4]=(short)f2bf(b1f.x); sh[5]=(short)f2bf(b1f.y); sh[6]=(short)f2bf(b1f.z); sh[7]=(short)f2bf(b1f.w);
      Wi[G][kf] = si; Wh[G][kf] = sh;
    }
  }
  float br  = bih[col]       + bhh[col];
  float bz  = bih[128 + col] + bhh[128 + col];
  float bin = bih[256 + col];               // bhh_n stays inside r*( ) per PyTorch GRU
  float bnh = bhh[256 + col];

  // init h from carry slot (zeroed by k_prep for chunk 0)
  float hold[4];
  #pragma unroll
  for (int r = 0; r < 4; r++) {
    int m = q * 4 + r;
    unsigned short u = myseq[((size_t)(tc - 1) * 1024 + b0 + m) * 128 + col];
    hold[r] = bf2f(u);
    hbuf[0][m][col] = u;
  }
  // stage x(t0), prefetch x(t0+1)
  int xrow = tid >> 5, xc4 = (tid & 31) * 4;
  {
    float4 x0 = ((const float4*)(x + ((size_t)t0 * 1024 + b0) * 128))[tid];
    *(uint2*)&xbuf[0][xrow][xc4] = make_uint2(pack2(x0.x, x0.y), pack2(x0.z, x0.w));
  }
  int tn = t0 + (tc > 1 ? 1 : 0);
  float4 xr = ((const float4*)(x + ((size_t)tn * 1024 + b0) * 128))[tid];
  __syncthreads();

  // hoisted output pointer: stores at opq[r*128] with immediate offsets
  unsigned short* opq = myseq + ((size_t)(b0 + q * 4)) * 128 + col;

  auto step = [&](int s, int pin, int pout) {
    // A-fragments from LDS (x first: feeds the off-critical-path x-MFMAs)
    short8 Ax[4], Ah[4];
    #pragma unroll
    for (int kf = 0; kf < 4; kf++) Ax[kf] = *(const short8*)&xbuf[pin][l15][kf * 32 + q * 8];
    #pragma unroll
    for (int kf = 0; kf < 4; kf++) Ah[kf] = *(const short8*)&hbuf[pin][l15][kf * 32 + q * 8];

    // commit prefetched x(s+1) (read of xbuf[pout] finished before last barrier)
    *(uint2*)&xbuf[pout][xrow][xc4] = make_uint2(pack2(xr.x, xr.y), pack2(xr.z, xr.w));
    // issue prefetch of x(s+2)
    {
      int t2 = t0 + (s + 2 < tc ? s + 2 : tc - 1);
      xr = ((const float4*)(x + ((size_t)t2 * 1024 + b0) * 128))[tid];
    }

    // six independent 4-deep MFMA chains
    float4v rx = (float4v){0.f,0.f,0.f,0.f}, zx = rx, nx = rx;
    float4v rh = rx, zh = rx, nh = rx;
    #pragma unroll
    for (int kf = 0; kf < 4; kf++) rx = __builtin_amdgcn_mfma_f32_16x16x32_bf16(Ax[kf], Wi[0][kf], rx, 0,0,0);
    #pragma unroll
    for (int kf = 0; kf < 4; kf++) zx = __builtin_amdgcn_mfma_f32_16x16x32_bf16(Ax[kf], Wi[1][kf], zx, 0,0,0);
    #pragma unroll
    for (int kf = 0; kf < 4; kf++) nx = __builtin_amdgcn_mfma_f32_16x16x32_bf16(Ax[kf], Wi[2][kf], nx, 0,0,0);
    #pragma unroll
    for (int kf = 0; kf < 4; kf++) rh = __builtin_amdgcn_mfma_f32_16x16x32_bf16(Ah[kf], Wh[0][kf], rh, 0,0,0);
    #pragma unroll
    for (int kf = 0; kf < 4; kf++) zh = __builtin_amdgcn_mfma_f32_16x16x32_bf16(Ah[kf], Wh[1][kf], zh, 0,0,0);
    #pragma unroll
    for (int kf = 0; kf < 4; kf++) nh = __builtin_amdgcn_mfma_f32_16x16x32_bf16(Ah[kf], Wh[2][kf], nh, 0,0,0);

    // x-side gate constants (off critical path: depend only on x-MFMAs)
    float cr[4], cz[4], cn[4];
    #pragma unroll
    for (int r = 0; r < 4; r++) { cr[r] = rx[r] + br; cz[r] = zx[r] + bz; cn[r] = nx[r] + bin; }

    // gates: shared-rcp sigmoid pair + exp-based tanh
    #pragma unroll
    for (int r = 0; r < 4; r++) {
      float er = __expf(-(rh[r] + cr[r]));
      float ez = __expf(-(zh[r] + cz[r]));
      float pr = 1.0f + er, pz = 1.0f + ez;
      float inv = __builtin_amdgcn_rcpf(pr * pz);
      float rr = pz * inv;                  // = 1/(1+er)
      float zz = pr * inv;                  // = 1/(1+ez)
      float y  = cn[r] + rr * (nh[r] + bnh);
      float em = __expf(-2.0f * y);
      float nn = 2.0f * __builtin_amdgcn_rcpf(1.0f + em) - 1.0f;   // tanh(y)
      float hn = nn + zz * (hold[r] - nn);
      hold[r] = hn;
      unsigned short hu = f2bf(hn);
      hbuf[pout][q * 4 + r][col] = hu;
      opq[r * 128] = hu;
    }
    opq += 131072;                          // advance one timestep (1024*128)
    LDS_BARRIER();
  };

  int s = 0;
  for (; s + 1 < tc; s += 2) { step(s, 0, 1); step(s + 1, 1, 0); }
  if (s < tc) step(s, 0, 1);
}

// ---------------- K2: attention score ----------------
// grid (tc, 2), block 512 (8 waves); each wave: 4 b-tiles of 16 rows.
__global__ __launch_bounds__(512) void k_score(const unsigned short* __restrict__ hl_seq,
                                               const unsigned short* __restrict__ hg_seq,
                                               const unsigned short* __restrict__ a12,
                                               const float* __restrict__ v1,
                                               float* __restrict__ score, int tc)
{
  __shared__ __align__(16) unsigned short M1[128][136];
  __shared__ __align__(16) unsigned short M2[128][136];
  int tid = threadIdx.x;
  int w = tid >> 6, L = tid & 63;
  int l15 = L & 15, q = L >> 4;
  int s = blockIdx.x;
  int bhalf = blockIdx.y * 512;

  // stage A1, A2 (bf16, pre-cast by k_prep) once: 4096 short8 over 512 thr
  #pragma unroll
  for (int it = 0; it < 4; it++) {
    int f8 = it * 512 + tid;                 // 0..2047
    *(short8*)&M1[f8 >> 4][(f8 & 15) * 8] = *(const short8*)(a12 + (size_t)f8 * 8);
    *(short8*)&M2[f8 >> 4][(f8 & 15) * 8] = *(const short8*)(a12 + 16384 + (size_t)f8 * 8);
  }
  __syncthreads();

  float v1v[8];
  #pragma unroll
  for (int nt = 0; nt < 8; nt++) v1v[nt] = v1[nt * 16 + l15];

  // 4 b-tiles per wave, 1-deep fragment prefetch
  short8 Fl[4], Fg[4], Pl[4], Pg[4];
  {
    size_t base = ((size_t)s * 1024 + bhalf + (size_t)w * 16 + l15) * 128;
    #pragma unroll
    for (int kf = 0; kf < 4; kf++) {
      Fl[kf] = *(const short8*)(hl_seq + base + kf * 32 + q * 8);
      Fg[kf] = *(const short8*)(hg_seq + base + kf * 32 + q * 8);
    }
  }
  #pragma unroll
  for (int it = 0; it < 4; it++) {
    int b0 = bhalf + (it * 8 + w) * 16;
    if (it + 1 < 4) {
      size_t base = ((size_t)s * 1024 + bhalf + (size_t)((it + 1) * 8 + w) * 16 + l15) * 128;
      #pragma unroll
      for (int kf = 0; kf < 4; kf++) {
        Pl[kf] = *(const short8*)(hl_seq + base + kf * 32 + q * 8);
        Pg[kf] = *(const short8*)(hg_seq + base + kf * 32 + q * 8);
      }
    }
    float4v acc[8];
    #pragma unroll
    for (int nt = 0; nt < 8; nt++) {
      float4v a = (float4v){0.f, 0.f, 0.f, 0.f};
      #pragma unroll
      for (int kf = 0; kf < 4; kf++)
        a = __builtin_amdgcn_mfma_f32_16x16x32_bf16(
            Fl[kf], *(const short8*)&M1[nt * 16 + l15][kf * 32 + q * 8], a, 0, 0, 0);
      #pragma unroll
      for (int kf = 0; kf < 4; kf++)
        a = __builtin_amdgcn_mfma_f32_16x16x32_bf16(
            Fg[kf], *(const short8*)&M2[nt * 16 + l15][kf * 32 + q * 8], a, 0, 0, 0);
      acc[nt] = a;
    }
    float p4[4];
    #pragma unroll
    for (int r = 0; r < 4; r++) {
      float sum = 0.f;
      #pragma unroll
      for (int nt = 0; nt < 8; nt++) sum += v1v[nt] * sigm(acc[nt][r]);
      sum += __shfl_xor(sum, 1, 16);
      sum += __shfl_xor(sum, 2, 16);
      sum += __shfl_xor(sum, 4, 16);
      sum += __shfl_xor(sum, 8, 16);
      p4[r] = sum;
    }
    if (l15 == 0) {
      #pragma unroll
      for (int r = 0; r < 4; r++)
        score[(size_t)(b0 + q * 4 + r) * tc + s] = p4[r];   // layout [b][tc]
    }
    #pragma unroll
    for (int kf = 0; kf < 4; kf++) { Fl[kf] = Pl[kf]; Fg[kf] = Pg[kf]; }
  }
}

// ---------------- K3: cumsum + capture (LDS-staged) ----------------
// grid 512, block 256: 2 batch rows/block, thread = (b2, j)
__global__ __launch_bounds__(256) void k_cum(const float* __restrict__ score,
                                             const unsigned short* __restrict__ hl_seq,
                                             const unsigned short* __restrict__ hg_seq,
                                             const int* __restrict__ lengths,
                                             float* __restrict__ cum,
                                             float* __restrict__ out, int tc, int t0)
{
  __shared__ __align__(16) unsigned short hlL[100 * 256];  // [s_seg][b2*128+j]
  __shared__ float scL[2][100];
  int tid = threadIdx.x;
  int b2 = tid >> 7, j = tid & 127;
  int b0 = blockIdx.x * 2;
  int b = b0 + b2;
  int base = b2 * 128 + j;

  float c = cum[(size_t)b * 128 + j];
  int cap0 = lengths[b] - 4;                // capture window [cap0, cap0+3] in [0,199]

  // preload the (<=4) h_g capture values that fall in this chunk
  float hgv[4];
  #pragma unroll
  for (int d = 0; d < 4; d++) {
    int sl = cap0 + d - t0;
    hgv[d] = (sl >= 0 && sl < tc) ? bf2f(hg_seq[((size_t)sl * 1024 + b) * 128 + j]) : 0.f;
  }

  for (int seg = 0; seg < tc; seg += 100) {
    int len = (tc - seg < 100) ? (tc - seg) : 100;
    __syncthreads();                         // protect LDS reuse across segments
    // stage hl rows [seg, seg+len) : coalesced short8
    for (int f8 = tid; f8 < len * 32; f8 += 256) {
      int sl = f8 >> 5, r8 = f8 & 31;
      *(short8*)&hlL[(size_t)f8 * 8] =
          *(const short8*)(hl_seq + ((size_t)(seg + sl) * 1024 + b0) * 128 + r8 * 8);
    }
    // stage score rows (contiguous per b: layout [b][tc])
    for (int i = tid; i < 2 * len; i += 256) {
      int bb = (i >= len) ? 1 : 0;
      int sl = i - bb * len;
      scL[bb][sl] = score[(size_t)(b0 + bb) * tc + seg + sl];
    }
    __syncthreads();

    int sl = 0;
    for (; sl + 5 <= len; sl += 5) {
      float h[5], sc[5];
      #pragma unroll
      for (int k = 0; k < 5; k++) {
        h[k] = bf2f(hlL[(size_t)(sl + k) * 256 + base]);
        sc[k] = scL[b2][sl + k];
      }
      #pragma unroll
      for (int k = 0; k < 5; k++) {
        c += sc[k] * h[k];
        int d = (t0 + seg + sl + k) - cap0;
        if ((unsigned)d < 4u)
          out[((size_t)b * 4 + d) * 128 + j] = c + hgv[d];
      }
    }
    for (; sl < len; sl++) {
      c += scL[b2][sl] * bf2f(hlL[(size_t)sl * 256 + base]);
      int d = (t0 + seg + sl) - cap0;
      if ((unsigned)d < 4u)
        out[((size_t)b * 4 + d) * 128 + j] = c + hgv[d];
    }
  }
  cum[(size_t)b * 128 + j] = c;
}

// ---------------- launch ----------------
extern "C" void kernel_launch(void* const* d_in, const int* in_sizes, int n_in,
                              void* d_out, int out_size, void* d_ws, size_t ws_size,
                              hipStream_t stream)
{
  const float* x     = (const float*)d_in[0];
  const int* lengths = (const int*)d_in[1];
  const float* Wih_g = (const float*)d_in[2];
  const float* Whh_g = (const float*)d_in[3];
  const float* bih_g = (const float*)d_in[4];
  const float* bhh_g = (const float*)d_in[5];
  const float* Wih_l = (const float*)d_in[6];
  const float* Whh_l = (const float*)d_in[7];
  const float* bih_l = (const float*)d_in[8];
  const float* bhh_l = (const float*)d_in[9];
  const float* A1    = (const float*)d_in[10];
  const float* A2    = (const float*)d_in[11];
  const float* v1    = (const float*)d_in[12];
  float* out = (float*)d_out;

  // fixed region: a12 bf16 (64KB) + cum (512KB)
  const size_t fixed = 65536 + 524288;
  const int cands[7] = {200, 100, 50, 10, 4, 2, 1};
  int tc = 0;
  for (int i = 0; i < 7; i++) {
    int T = cands[i];
    size_t need = 2 * (size_t)T * 1024 * 128 * 2   // hl, hg bf16
                + (size_t)T * 1024 * 4             // score fp32 [b][tc]
                + fixed;
    if (need <= ws_size) { tc = T; break; }
  }
  if (!tc) return;

  char* wsb = (char*)d_ws;
  size_t o = 0;
  unsigned short* a12 = (unsigned short*)(wsb + o); o += 65536;
  float* cum   = (float*)(wsb + o); o += 524288;
  unsigned short* hl  = (unsigned short*)(wsb + o); o += (size_t)tc * 1024 * 128 * 2;
  unsigned short* hg  = (unsigned short*)(wsb + o); o += (size_t)tc * 1024 * 128 * 2;
  float* score = (float*)(wsb + o);

  unsigned short* hl_slot = hl + (size_t)(tc - 1) * 1024 * 128;
  unsigned short* hg_slot = hg + (size_t)(tc - 1) * 1024 * 128;

  k_prep<<<512, 256, 0, stream>>>(hl_slot, hg_slot, cum, A1, A2, a12);
  int nch = 200 / tc;
  for (int c = 0; c < nch; c++) {
    k_scan<<<128, 512, 0, stream>>>(x, Wih_g, Whh_g, bih_g, bhh_g,
                                    Wih_l, Whh_l, bih_l, bhh_l, hl, hg, tc, c * tc);
    k_score<<<dim3(tc, 2), 512, 0, stream>>>(hl, hg, a12, v1, score, tc);
    k_cum<<<512, 256, 0, stream>>>(score, hl, hg, lengths, cum, out, tc, c * tc);
  }
}